// Round 8
// baseline (12109.329 us; speedup 1.0000x reference)
//
#include <hip/hip_runtime.h>
#include <hip/hip_bf16.h>

// 5-layer LSTM, B=64, T=256, H=1024. bf16 MFMA (16x16x32), fp32 state.
// Round 8: r7 design (barrier-free t-loop, swapped MFMA, lane-local epilogue)
// with hardened launch mechanics:
//  - __launch_bounds__(256,2) (VGPR cap 256; standard occupancy shape)
//  - error-checked cooperative launch + plain-launch fallback
//  - early-clobber poll destination; seqB zero-init diagnostic sentinel

using bf16x8 = __attribute__((ext_vector_type(8))) __bf16;
using f32x4  = __attribute__((ext_vector_type(4))) float;
using u32x2  = __attribute__((ext_vector_type(2))) unsigned;

#define Tn 256
#define Bn 64
#define Hn 1024

#define MFMA16(a, b, c) __builtin_amdgcn_mfma_f32_16x16x32_bf16((a), (b), (c), 0, 0, 0)

// ---------------------------------------------------------------------------
// Wg[l][k][unit] fp32 -> Wperm A-frag-linear bf16.
// Per (l,cb) a 128 KiB slab of 128 frags x 64 lanes x 16 B.
// frag = (p*2+nt)*32 + kt   (p: 0=x,1=h; nt: unit sub-block; kt: K/32 step)
// lane = lhi*16 + c16, c16 = u4*4 + g  (gate g in A-row bits -> D-row j)
// element (gate-col c16 of unit cb*8+nt*4+u4, k = p*1024 + kt*32 + lhi*8 + j)
__global__ void convW(const float* __restrict__ Wi, const float* __restrict__ Wf,
                      const float* __restrict__ Wc, const float* __restrict__ Wo,
                      __bf16* __restrict__ Wperm) {
    int gid = blockIdx.x * 256 + threadIdx.x;      // 5*1024*4*256 = 5,242,880
    int k8   = gid & 255;                          // 8-k chunk: k = k8*8
    int g    = (gid >> 8) & 3;
    int unit = (gid >> 10) & 1023;
    int l    = gid >> 20;
    const float* Wg = (g == 0) ? Wi : (g == 1) ? Wf : (g == 2) ? Wc : Wo;
    const float* src = Wg + ((size_t)l * 2048 + k8 * 8) * 1024 + unit;
    bf16x8 v;
#pragma unroll
    for (int j = 0; j < 8; ++j) v[j] = (__bf16)src[(size_t)j * 1024];
    int cb = unit >> 3, nt = (unit >> 2) & 1, u4 = unit & 3;
    int c16 = u4 * 4 + g;
    int p = k8 >> 7, kt = (k8 >> 2) & 31, lhi = k8 & 3;
    int lane = lhi * 16 + c16;
    int frag = (p * 2 + nt) * 32 + kt;
    size_t dst = ((size_t)(l * 128 + cb) * 128 + frag) * 1024 + lane * 16;
    *(bf16x8*)((char*)Wperm + dst) = v;
}

// x[b][t][k] fp32 -> seq[t][b][k] bf16
__global__ void convX(const float* __restrict__ x, __bf16* __restrict__ seq) {
    int gid = blockIdx.x * 256 + threadIdx.x;      // 2,097,152
    int k8 = gid & 127;
    int b  = (gid >> 7) & 63;
    int t  = gid >> 13;
    const float* src = x + ((size_t)b * Tn + t) * Hn + k8 * 8;
    bf16x8 v;
#pragma unroll
    for (int j = 0; j < 8; ++j) v[j] = (__bf16)src[j];
    *(bf16x8*)(seq + (size_t)gid * 8) = v;
}

// ---------------------------------------------------------------------------
__device__ __forceinline__ void store_coh_u32x2(void* p, u32x2 v) {
    asm volatile("global_store_dwordx2 %0, %1, off sc0 sc1" :: "v"(p), "v"(v) : "memory");
}
__device__ __forceinline__ void store_coh_u16(void* p, unsigned v) {
    asm volatile("global_store_short %0, %1, off sc0 sc1" :: "v"(p), "v"(v) : "memory");
}

// poll own 256-flag group (u16 each), 4 flags/lane, backoff on failure
__device__ __forceinline__ void pollwait(const char* p, unsigned target) {
    while (true) {
        u32x2 v;
        asm volatile("global_load_dwordx2 %0, %1, off sc0 sc1\n\ts_waitcnt vmcnt(0)"
                     : "=&v"(v) : "v"(p) : "memory");
        unsigned w0 = v[0], w1 = v[1];
        bool ok = ((w0 & 0xFFFFu) >= target) && ((w0 >> 16) >= target) &&
                  ((w1 & 0xFFFFu) >= target) && ((w1 >> 16) >= target);
        if (__all((int)ok)) break;
        __builtin_amdgcn_s_sleep(1);
    }
}

// fast gates: v_exp_f32 computes 2^x; v_rcp_f32 ~1ulp
__device__ __forceinline__ float fsigmoid(float z) {
    return __builtin_amdgcn_rcpf(1.f + __builtin_amdgcn_exp2f(-1.44269504089f * z));
}
__device__ __forceinline__ float ftanh(float z) {
    return 1.f - 2.f * __builtin_amdgcn_rcpf(1.f + __builtin_amdgcn_exp2f(2.88539008178f * z));
}

// ---------------------------------------------------------------------------
// Persistent kernel. 256 blocks x 256 threads (4 waves), 1 block/CU.
// Block (rb = bid&1: batch half, cb = bid>>1: units [8cb,8cb+8)).
// Wave w: ms = w&1 (16-row slice), nt = w>>1 (4-unit sub-block).
// Lane (lhi = lane>>4, l15 = lane&15) owns (batch row l15 of its slice,
// unit cb*8+nt*4+lhi); acc[j] = gate j in {i,f,g,o}. Flag groups (rb,ms):
// 256 u16 flags; wave polls/produces only within its group.
__global__ __launch_bounds__(256, 2) void lstm_all(
    __bf16* __restrict__ seqA, __bf16* __restrict__ seqB,
    const __bf16* __restrict__ Wperm,
    const float* __restrict__ bip, const float* __restrict__ bfp,
    const float* __restrict__ bcp, const float* __restrict__ bop,
    unsigned short* __restrict__ bar) {
    extern __shared__ char smem[];                 // 64 KiB x-part weight slab

    const int tid  = threadIdx.x;
    const int bid  = blockIdx.x;
    const int rb   = bid & 1;
    const int cb   = bid >> 1;
    const int w    = tid >> 6;
    const int lane = tid & 63;
    const int ms   = w & 1;
    const int nt   = w >> 1;
    const int l15  = lane & 15;
    const int lhi  = lane >> 4;
    const int row  = rb * 32 + ms * 16 + l15;      // batch row (B-frag col)
    const int grp  = rb * 2 + ms;

    unsigned short* myflag = bar + (grp * 128 + cb) * 2 + nt;
    const char* pollp = (const char*)bar + grp * 512 + lane * 8;

    __bf16* inp  = seqA;
    __bf16* outp = seqB;

    for (int l = 0; l < 5; ++l) {
        __syncthreads();                           // old x-slab no longer read
        pollwait(pollp, (unsigned)(l * Tn));       // prev layer complete (l=0 trivial)
        __builtin_amdgcn_fence(__ATOMIC_ACQUIRE, "agent");   // inv L1/L2

        const char* Wl = (const char*)Wperm + (size_t)(l * 128 + cb) * 131072;
        // stage x-part slab (first 64 KiB) into LDS
#pragma unroll
        for (int it = 0; it < 16; ++it) {
            int off = it * 4096 + tid * 16;
            *(bf16x8*)(smem + off) = *(const bf16x8*)(Wl + off);
        }
        // h-part A-frags into VGPRs (32 x bf16x8 = 128 VGPR)
        bf16x8 bh[32];
#pragma unroll
        for (int kt = 0; kt < 32; ++kt)
            bh[kt] = *(const bf16x8*)(Wl + (size_t)((2 + nt) * 32 + kt) * 1024
                                         + lane * 16);
        const int unit = cb * 8 + nt * 4 + lhi;
        const float bia0 = bip[l * 1024 + unit];
        const float bia1 = bfp[l * 1024 + unit];
        const float bia2 = bcp[l * 1024 + unit];
        const float bia3 = bop[l * 1024 + unit];
        float creg = 0.f;
        __syncthreads();                           // x-slab staged

        f32x4 acc0 = {}, acc1 = {};
        {   // x-part for t = 0
            const __bf16* xb = inp + (size_t)row * Hn + lhi * 8;
#pragma unroll
            for (int kt = 0; kt < 32; kt += 2) {
                bf16x8 a0 = *(const bf16x8*)(smem + (nt * 32 + kt) * 1024 + lane * 16);
                bf16x8 a1 = *(const bf16x8*)(smem + (nt * 32 + kt + 1) * 1024 + lane * 16);
                bf16x8 b0 = *(const bf16x8*)(xb + kt * 32);
                bf16x8 b1 = *(const bf16x8*)(xb + kt * 32 + 32);
                acc0 = MFMA16(a0, b0, acc0);
                acc1 = MFMA16(a1, b1, acc1);
            }
        }

        for (int t = 0; t < Tn; ++t) {
            if (t > 0) {
                pollwait(pollp, (unsigned)(l * Tn + t));
                // h-part GEMM: B = h[t-1] rows (normal cached, L2 broadcast),
                // A = bh VGPRs. Two accumulation chains.
                const __bf16* hb = outp + ((size_t)(t - 1) * Bn + row) * Hn + lhi * 8;
#pragma unroll
                for (int kt = 0; kt < 32; kt += 2) {
                    bf16x8 b0 = *(const bf16x8*)(hb + kt * 32);
                    bf16x8 b1 = *(const bf16x8*)(hb + kt * 32 + 32);
                    acc0 = MFMA16(bh[kt], b0, acc0);
                    acc1 = MFMA16(bh[kt + 1], b1, acc1);
                }
            }
            // ---- lane-local epilogue: acc[j] = gate j for (row, unit)
            float zi = acc0[0] + acc1[0] + bia0;
            float zf = acc0[1] + acc1[1] + bia1;
            float zg = acc0[2] + acc1[2] + bia2;
            float zo = acc0[3] + acc1[3] + bia3;
            float ii = fsigmoid(zi);
            float ff = fsigmoid(zf);
            float gg = ftanh(zg);
            float oo = fsigmoid(zo);
            creg = creg * ff + ii * gg;
            float hv = oo * ftanh(creg);
            // pack 4 units of one row (lhi 0..3) -> dwordx2 at lanes < 16
            unsigned hb16 = (unsigned)__builtin_bit_cast(unsigned short, (__bf16)hv);
            unsigned d = hb16 | ((unsigned)__shfl_xor((int)hb16, 16) << 16);
            unsigned e = (unsigned)__shfl_xor((int)d, 32);
            if (lane < 16) {
                u32x2 v2 = {d, e};
                store_coh_u32x2(outp + ((size_t)t * Bn + row) * Hn + cb * 8 + nt * 4, v2);
            }
            asm volatile("s_waitcnt vmcnt(0)" ::: "memory");   // h at L3
            if (lane == 0)
                store_coh_u16(myflag, (unsigned)(l * Tn + t + 1));
            // ---- x-part for t+1 (independent of h -> hides flag latency)
            acc0 = (f32x4){}; acc1 = (f32x4){};
            if (t < Tn - 1) {
                const __bf16* xb = inp + ((size_t)(t + 1) * Bn + row) * Hn + lhi * 8;
#pragma unroll
                for (int kt = 0; kt < 32; kt += 2) {
                    bf16x8 a0 = *(const bf16x8*)(smem + (nt * 32 + kt) * 1024 + lane * 16);
                    bf16x8 a1 = *(const bf16x8*)(smem + (nt * 32 + kt + 1) * 1024 + lane * 16);
                    bf16x8 b0 = *(const bf16x8*)(xb + kt * 32);
                    bf16x8 b1 = *(const bf16x8*)(xb + kt * 32 + 32);
                    acc0 = MFMA16(a0, b0, acc0);
                    acc1 = MFMA16(a1, b1, acc1);
                }
            }
        }
        __bf16* tmp = outp; outp = inp; inp = tmp; // ping-pong
    }
}

// ---------------------------------------------------------------------------
// out[b] = dot(h5[T-1][b][:], Wfc) + bfc
__global__ void fc_kernel(const __bf16* __restrict__ seq, const float* __restrict__ Wfc,
                          const float* __restrict__ bfc, float* __restrict__ out) {
    int b = blockIdx.x;
    int tid = threadIdx.x;
    const __bf16* h = seq + ((size_t)(Tn - 1) * Bn + b) * Hn;
    float s = 0.f;
    for (int k = tid; k < Hn; k += 256) s += (float)h[k] * Wfc[k];
#pragma unroll
    for (int off = 32; off > 0; off >>= 1) s += __shfl_down(s, off);
    __shared__ float red[4];
    if ((tid & 63) == 0) red[tid >> 6] = s;
    __syncthreads();
    if (tid == 0) out[b] = red[0] + red[1] + red[2] + red[3] + bfc[0];
}

// ---------------------------------------------------------------------------
extern "C" void kernel_launch(void* const* d_in, const int* in_sizes, int n_in,
                              void* d_out, int out_size, void* d_ws, size_t ws_size,
                              hipStream_t stream) {
    const float* x   = (const float*)d_in[0];
    const float* Wi  = (const float*)d_in[1];
    const float* bi  = (const float*)d_in[2];
    const float* Wf  = (const float*)d_in[3];
    const float* bf  = (const float*)d_in[4];
    const float* Wc  = (const float*)d_in[5];
    const float* bc  = (const float*)d_in[6];
    const float* Wo  = (const float*)d_in[7];
    const float* bo  = (const float*)d_in[8];
    const float* Wfc = (const float*)d_in[9];
    const float* bfc = (const float*)d_in[10];

    char* ws = (char*)d_ws;
    __bf16*         Wperm = (__bf16*)ws;                               // 83,886,080 B
    __bf16*         seqA  = (__bf16*)(ws + 83886080);                  // 33,554,432 B
    __bf16*         seqB  = (__bf16*)(ws + 83886080 + 33554432);       // 33,554,432 B
    unsigned short* bar   = (unsigned short*)(ws + 83886080 + 2 * 33554432); // 2,048 B

    hipFuncSetAttribute((const void*)lstm_all,
                        hipFuncAttributeMaxDynamicSharedMemorySize, 65536);

    hipLaunchKernelGGL(convW, dim3(20480), dim3(256), 0, stream, Wi, Wf, Wc, Wo, Wperm);
    hipLaunchKernelGGL(convX, dim3(8192), dim3(256), 0, stream, x, seqA);
    hipMemsetAsync(bar, 0, 2048, stream);
    hipMemsetAsync(seqB, 0, 33554432, stream);  // sentinel: "didn't run" => exact-ref absmax

    void* args[] = {(void*)&seqA, (void*)&seqB, (void*)&Wperm,
                    (void*)&bi, (void*)&bf, (void*)&bc, (void*)&bo, (void*)&bar};
    hipError_t ce = hipLaunchCooperativeKernel((const void*)lstm_all, dim3(256),
                                               dim3(256), args, 65536, stream);
    if (ce != hipSuccess) {
        // fallback: plain launch. grid (256) <= resident capacity (>=1 block/CU
        // at 64 KiB LDS + <=256 VGPR), so all blocks are co-resident anyway and
        // the flag protocol cannot deadlock.
        hipLaunchKernelGGL(lstm_all, dim3(256), dim3(256), 65536, stream,
                           seqA, seqB, (const __bf16*)Wperm, bi, bf, bc, bo, bar);
    }

    // after 5 ping-pongs the final hidden sequence is in seqB
    hipLaunchKernelGGL(fc_kernel, dim3(64), dim3(256), 0, stream, seqB, Wfc, bfc,
                       (float*)d_out);
}